// Round 14
// baseline (68.467 us; speedup 1.0000x reference)
//
#include <hip/hip_runtime.h>
#include <math.h>

#define B_    8
#define N_    1024
#define FIN   512
#define FOUT  256
#define ALPHA 0.2f
#define EPSV  1e-5f

typedef __attribute__((ext_vector_type(8))) short bf16x8;
typedef __attribute__((ext_vector_type(4))) float f32x4;

__device__ __forceinline__ short f2bf(float x) {          // RNE
    unsigned u = __builtin_bit_cast(unsigned, x);
    u = (u + 0x7FFFu + ((u >> 16) & 1u)) >> 16;
    return (short)u;
}
__device__ __forceinline__ short f2bf_fast(float x) {     // round-half-up (P path)
    unsigned u = __builtin_bit_cast(unsigned, x);
    return (short)((u + 0x8000u) >> 16);
}
__device__ __forceinline__ float bf2f(short s) {
    return __builtin_bit_cast(float, ((unsigned)(unsigned short)s) << 16);
}
__device__ __forceinline__ float gelu_exact(float x) {
    return 0.5f * x * (1.0f + erff(x * 0.70710678118654752f));
}

// Fragment-linear chunks (1 KB = 64 lanes x 16B):
//   Apack[b][m16][kt][l][u8] : lane l=(lq*16+lr) holds P[m16*16+lr][kt*32+lq*8+u]
//   Bpack[b][n16][kt][l][u8] : lane l=(lq*16+lr) holds Wh[kt*32+lq*8+u][n16*16+lr]
// Bit matrix: byte bits[row*128 + lq*32 + kt] = adj bits for j = kt*32+lq*8+u.

// ---------------------------------------------------------------------------
// k_prep: W (512x256 fp32 row-major) -> WT (256x512 bf16, [col][k]).
// ---------------------------------------------------------------------------
__global__ __launch_bounds__(256) void k_prep(const float* __restrict__ W,
                                              short* __restrict__ WT) {
    int id  = blockIdx.x * 256 + threadIdx.x;
    int col = id >> 7;
    int k4  = (id & 127) * 4;
    short4 v;
    v.x = f2bf(W[(k4 + 0) * FOUT + col]);
    v.y = f2bf(W[(k4 + 1) * FOUT + col]);
    v.z = f2bf(W[(k4 + 2) * FOUT + col]);
    v.w = f2bf(W[(k4 + 3) * FOUT + col]);
    *(short4*)(WT + (long)col * FIN + k4) = v;
}

// ---------------------------------------------------------------------------
// k_bits: adj (read once, coalesced) -> bitmask in A-frag byte order.
// One wave per row. Grid = 2048.
// ---------------------------------------------------------------------------
__global__ __launch_bounds__(256) void k_bits(const float* __restrict__ adj,
                                              unsigned char* __restrict__ bits) {
    const int tid = threadIdx.x;
    const int w   = tid >> 6, l = tid & 63;
    const long gr = (long)blockIdx.x * 4 + w;
    const float* __restrict__ arow = adj + gr * N_;

    unsigned b0 = 0, b1 = 0;
    {
        float4 x0 = *(const float4*)(arow + l * 8);
        float4 x1 = *(const float4*)(arow + l * 8 + 4);
        float aa[8] = {x0.x, x0.y, x0.z, x0.w, x1.x, x1.y, x1.z, x1.w};
        #pragma unroll
        for (int u = 0; u < 8; ++u) b0 |= (aa[u] > 0.f ? 1u : 0u) << u;
        float4 y0 = *(const float4*)(arow + 512 + l * 8);
        float4 y1 = *(const float4*)(arow + 512 + l * 8 + 4);
        float bb[8] = {y0.x, y0.y, y0.z, y0.w, y1.x, y1.y, y1.z, y1.w};
        #pragma unroll
        for (int u = 0; u < 8; ++u) b1 |= (bb[u] > 0.f ? 1u : 0u) << u;
    }
    unsigned out2 = 0;
    #pragma unroll
    for (int k = 0; k < 2; ++k) {
        int o   = 2 * l + k;
        int lqd = o >> 5, ktd = o & 31;
        int src = ((ktd & 15) << 2) | lqd;
        unsigned v0 = __shfl(b0, src, 64);
        unsigned v1 = __shfl(b1, src, 64);
        unsigned v  = (ktd & 16) ? v1 : v0;
        out2 |= (v & 0xFFu) << (8 * k);
    }
    *(unsigned short*)(bits + gr * 128 + l * 2) = (unsigned short)out2;
}

// ---------------------------------------------------------------------------
// k_wh: Wh = h @ W via bf16 MFMA; writes Bpack (fragment-linear) + F1/F2.
// ---------------------------------------------------------------------------
__global__ __launch_bounds__(256) void k_wh(const float* __restrict__ h,
                                            const short* __restrict__ WT,
                                            const float* __restrict__ a,
                                            short* __restrict__ Bpack,
                                            float* __restrict__ F1,
                                            float* __restrict__ F2) {
    const int tid = threadIdx.x;
    const int w   = tid >> 6, l = tid & 63;
    const int lr  = l & 15, lq = l >> 4;
    const long row0 = (long)blockIdx.x * 16;
    const int colbase = w * 64;

    __shared__ float r1[4][16], r2[4][16];

    f32x4 acc[4] = {};
    const float* hrow = h + (row0 + lr) * FIN + lq * 8;

    #pragma unroll
    for (int k0 = 0; k0 < FIN; k0 += 32) {
        float4 v0 = *(const float4*)(hrow + k0);
        float4 v1 = *(const float4*)(hrow + k0 + 4);
        bf16x8 af;
        af[0] = f2bf(v0.x); af[1] = f2bf(v0.y); af[2] = f2bf(v0.z); af[3] = f2bf(v0.w);
        af[4] = f2bf(v1.x); af[5] = f2bf(v1.y); af[6] = f2bf(v1.z); af[7] = f2bf(v1.w);
        #pragma unroll
        for (int c = 0; c < 4; ++c) {
            const short* bp = WT + (long)(colbase + c * 16 + lr) * FIN + k0 + lq * 8;
            bf16x8 bf = *(const bf16x8*)bp;
            acc[c] = __builtin_amdgcn_mfma_f32_16x16x32_bf16(af, bf, acc[c], 0, 0, 0);
        }
    }

    const int b   = (int)(row0 >> 10);
    const int il0 = (int)(row0 & 1023);
    const int kt  = il0 >> 5;
    const int h16 = (il0 >> 4) & 1;
    const int lp  = (h16 * 2 + (lq >> 1)) * 16 + lr;
    const int u0  = (lq & 1) * 4;
    short* bpo = Bpack + ((long)b * 16 * 32) * 512;
    #pragma unroll
    for (int c = 0; c < 4; ++c) {
        short4 s;
        s.x = f2bf(acc[c][0]); s.y = f2bf(acc[c][1]);
        s.z = f2bf(acc[c][2]); s.w = f2bf(acc[c][3]);
        int n16 = w * 4 + c;
        *(short4*)(bpo + ((long)(n16 * 32 + kt)) * 512 + lp * 8 + u0) = s;
    }

    float p1[4] = {0.f, 0.f, 0.f, 0.f}, p2[4] = {0.f, 0.f, 0.f, 0.f};
    #pragma unroll
    for (int c = 0; c < 4; ++c) {
        int col = colbase + c * 16 + lr;
        float a1v = a[col], a2v = a[FOUT + col];
        #pragma unroll
        for (int j = 0; j < 4; ++j) { p1[j] += acc[c][j] * a1v; p2[j] += acc[c][j] * a2v; }
    }
    #pragma unroll
    for (int off = 1; off < 16; off <<= 1) {
        #pragma unroll
        for (int j = 0; j < 4; ++j) {
            p1[j] += __shfl_xor(p1[j], off, 64);
            p2[j] += __shfl_xor(p2[j], off, 64);
        }
    }
    if (lr == 0) {
        #pragma unroll
        for (int j = 0; j < 4; ++j) { r1[w][lq * 4 + j] = p1[j]; r2[w][lq * 4 + j] = p2[j]; }
    }
    __syncthreads();
    if (tid < 16) {
        F1[row0 + tid] = r1[0][tid] + r1[1][tid] + r1[2][tid] + r1[3][tid];
        F2[row0 + tid] = r2[0][tid] + r2[1][tid] + r2[2][tid] + r2[3][tid];
    }
}

// ---------------------------------------------------------------------------
// k_pgen v4: Apack = bit ? exp(leaky(f1+f2)) : 0 (bf16, m=0 softmax) + lrow
// (row sums of quantized P). Block = (b, m16); wave w covers kt w*8..+7.
// Streaming 1KB/wave writes. Grid = (8, 64).
// ---------------------------------------------------------------------------
__global__ __launch_bounds__(256) void k_pgen(const unsigned char* __restrict__ bits,
                                              const float* __restrict__ F1,
                                              const float* __restrict__ F2,
                                              short* __restrict__ Apack,
                                              float* __restrict__ lrow) {
    const int tid = threadIdx.x;
    const int b   = blockIdx.x;
    const int m16 = blockIdx.y;
    const int i0  = m16 * 16;
    const int w   = tid >> 6, l = tid & 63;
    const int lr  = l & 15, lq = l >> 4;

    __shared__ float f2s[N_];
    __shared__ float lred[4][16];
    { int j = tid * 4; *(float4*)&f2s[j] = *(const float4*)(F2 + b * N_ + j); }
    __syncthreads();

    const float f1 = F1[b * N_ + i0 + lr];
    const uint2 bw2 = *(const uint2*)(bits + ((long)(b * N_ + i0 + lr)) * 128 + lq * 32 + w * 8);
    const unsigned bwv[2] = {bw2.x, bw2.y};
    short* __restrict__ apb = Apack + (((long)b * 64 + m16) * 32) * 512;

    float ls = 0.f;
    #pragma unroll
    for (int it = 0; it < 8; ++it) {
        const int kt = w * 8 + it;
        const unsigned byte = (bwv[it >> 2] >> ((it & 3) * 8)) & 0xFFu;
        float f2k[8];
        *(float4*)&f2k[0] = *(const float4*)&f2s[kt * 32 + lq * 8];
        *(float4*)&f2k[4] = *(const float4*)&f2s[kt * 32 + lq * 8 + 4];
        bf16x8 pv;
        #pragma unroll
        for (int u = 0; u < 8; ++u) {
            float x  = f1 + f2k[u];
            float tt = fmaxf(x, ALPHA * x);
            float e  = ((byte >> u) & 1u) ? __expf(tt) : 0.f;
            short s  = f2bf_fast(e);
            pv[u] = s;
            ls += bf2f(s);
        }
        *(bf16x8*)(apb + (long)kt * 512 + l * 8) = pv;
    }

    ls += __shfl_xor(ls, 16, 64);
    ls += __shfl_xor(ls, 32, 64);
    if (lq == 0) lred[w][lr] = ls;
    __syncthreads();
    if (tid < 16)
        lrow[(long)b * N_ + i0 + tid] = lred[0][tid] + lred[1][tid] + lred[2][tid] + lred[3][tid];
}

// ---------------------------------------------------------------------------
// k_pv v6: 2-phase LDS-staged GEMM (T3-minimum template). Block = 128 thr /
// 2 col-waves; wave tile 32 rows x 64 cols (2x4 frags: B reused x2, A x4;
// 0.56 KB/MFMA). K-step 64 (2 kt): stage 20 x 1KB chunks via
// global_load_lds into 40KB dbuf LDS; one __syncthreads per step. Grid =
// (256, 2) -> 2 blocks/CU. blockIdx.x swizzled so XCD k only touches batch
// k's 512KB Bpack slab (L2-resident). Writes RAW PV sums to out (k_ln
// finishes in-place).
// ---------------------------------------------------------------------------
__global__ __launch_bounds__(128) void k_pv(const short* __restrict__ Apack,
                                            const short* __restrict__ Bpack,
                                            float* __restrict__ hp) {
    const int tid = threadIdx.x;
    const int w   = tid >> 6, l = tid & 63;
    const int lr  = l & 15, lq = l >> 4;
    const int rg  = ((blockIdx.x & 7) << 5) | (blockIdx.x >> 3);   // XCD=batch pin
    const int b   = rg >> 5;
    const int rloc= rg & 31;
    const int cg  = blockIdx.y;

    __shared__ short sbuf[2][20 * 512];    // 40 KB: chunks 0-3 = A, 4-19 = B

    const short* __restrict__ abase = Apack + (((long)b * 64 + rloc * 2) * 32) * 512 + (long)l * 8;
    const short* __restrict__ bbase = Bpack + (((long)b * 16 + cg * 8) * 32) * 512 + (long)l * 8;

    f32x4 acc[2][4] = {};

    // stage K-step t into buffer `buf`: chunks c = w, w+2, ... (10 per wave)
    auto stage = [&](int buf, int t) {
        const int kt0 = t * 2;
        #pragma unroll
        for (int c = w; c < 20; c += 2) {
            const short* src;
            if (c < 4) {
                src = abase + ((long)(c >> 1) * 32 + kt0 + (c & 1)) * 512;
            } else {
                int idx = c - 4;
                src = bbase + ((long)(idx >> 1) * 32 + kt0 + (idx & 1)) * 512;
            }
            __builtin_amdgcn_global_load_lds(
                (const __attribute__((address_space(1))) unsigned int*)src,
                (__attribute__((address_space(3))) unsigned int*)&sbuf[buf][c * 512],
                16, 0, 0);
        }
    };

    auto compute = [&](int buf) {
        #pragma unroll
        for (int kt2 = 0; kt2 < 2; ++kt2) {
            bf16x8 a0 = *(const bf16x8*)&sbuf[buf][(0 + kt2) * 512 + l * 8];
            bf16x8 a1 = *(const bf16x8*)&sbuf[buf][(2 + kt2) * 512 + l * 8];
            #pragma unroll
            for (int cf = 0; cf < 4; ++cf) {
                const int n = w * 4 + cf;
                bf16x8 bv = *(const bf16x8*)&sbuf[buf][(4 + n * 2 + kt2) * 512 + l * 8];
                acc[0][cf] = __builtin_amdgcn_mfma_f32_16x16x32_bf16(a0, bv, acc[0][cf], 0, 0, 0);
                acc[1][cf] = __builtin_amdgcn_mfma_f32_16x16x32_bf16(a1, bv, acc[1][cf], 0, 0, 0);
            }
        }
    };

    stage(0, 0);
    __syncthreads();                       // drains vmcnt(0): buf0 ready
    int cur = 0;
    for (int t = 0; t < 16; ++t) {
        if (t < 15) stage(cur ^ 1, t + 1); // async loads overlap compute
        compute(cur);
        __syncthreads();                   // drains vmcnt+lgkm: next buf ready
        cur ^= 1;
    }

    const long row0 = (long)b * 1024 + (long)rloc * 32;
    const int  c0   = cg * 128 + w * 64;
    #pragma unroll
    for (int rf = 0; rf < 2; ++rf)
        #pragma unroll
        for (int cf = 0; cf < 4; ++cf)
            #pragma unroll
            for (int jj = 0; jj < 4; ++jj)
                hp[(row0 + rf * 16 + lq * 4 + jj) * FOUT + c0 + cf * 16 + lr] = acc[rf][cf][jj];
}

// ---------------------------------------------------------------------------
// k_ln: in-place (1/l) + LayerNorm + GELU on out. Block = 256 thr = 8 rows
// x 32 lanes (8 cols each). Row-private -> safe in-place. Grid = 1024.
// ---------------------------------------------------------------------------
__global__ __launch_bounds__(256) void k_ln(float* __restrict__ hp,
                                            const float* __restrict__ lrow,
                                            const float* __restrict__ gamma,
                                            const float* __restrict__ beta) {
    const int tid = threadIdx.x;
    const long row = (long)blockIdx.x * 8 + (tid >> 5);
    const int sub = tid & 31, f0 = sub * 8;

    float* p = hp + row * FOUT + f0;
    float4 v0 = *(const float4*)p;
    float4 v1 = *(const float4*)(p + 4);
    float lv = lrow[row];
    float il = (lv > 0.f) ? 1.0f / lv : 0.f;
    float v[8] = {v0.x, v0.y, v0.z, v0.w, v1.x, v1.y, v1.z, v1.w};
    float s1 = 0.f, s2 = 0.f;
    #pragma unroll
    for (int u = 0; u < 8; ++u) { v[u] *= il; s1 += v[u]; s2 += v[u] * v[u]; }
    #pragma unroll
    for (int off = 1; off < 32; off <<= 1) {
        s1 += __shfl_xor(s1, off, 64);
        s2 += __shfl_xor(s2, off, 64);
    }
    const float mu   = s1 * (1.0f / FOUT);
    const float rstd = rsqrtf(s2 * (1.0f / FOUT) - mu * mu + EPSV);

    float4 g0 = *(const float4*)(gamma + f0);
    float4 g1 = *(const float4*)(gamma + f0 + 4);
    float4 b0 = *(const float4*)(beta + f0);
    float4 b1 = *(const float4*)(beta + f0 + 4);
    float4 o0, o1;
    o0.x = gelu_exact((v[0] - mu) * rstd * g0.x + b0.x);
    o0.y = gelu_exact((v[1] - mu) * rstd * g0.y + b0.y);
    o0.z = gelu_exact((v[2] - mu) * rstd * g0.z + b0.z);
    o0.w = gelu_exact((v[3] - mu) * rstd * g0.w + b0.w);
    o1.x = gelu_exact((v[4] - mu) * rstd * g1.x + b1.x);
    o1.y = gelu_exact((v[5] - mu) * rstd * g1.y + b1.y);
    o1.z = gelu_exact((v[6] - mu) * rstd * g1.z + b1.z);
    o1.w = gelu_exact((v[7] - mu) * rstd * g1.w + b1.w);
    *(float4*)p       = o0;
    *(float4*)(p + 4) = o1;
}

extern "C" void kernel_launch(void* const* d_in, const int* in_sizes, int n_in,
                              void* d_out, int out_size, void* d_ws, size_t ws_size,
                              hipStream_t stream) {
    const float* h     = (const float*)d_in[0];
    const float* adj   = (const float*)d_in[1];
    // d_in[2]=q_type, d_in[3]=pos : unused scalars
    const float* W     = (const float*)d_in[4];
    const float* a     = (const float*)d_in[5];
    const float* gamma = (const float*)d_in[6];
    const float* beta  = (const float*)d_in[7];
    float* out = (float*)d_out;

    // workspace layout (~21.4 MB)
    short* Apack = (short*)d_ws;                          // 16 MB
    short* Bpack = Apack + (size_t)B_ * 64 * 32 * 512;    // 4 MB
    short* WT    = Bpack + (size_t)B_ * 16 * 32 * 512;    // 256 KB
    float* F1    = (float*)(WT + (size_t)FOUT * FIN);     // 32 KB
    float* F2    = F1 + (size_t)B_ * N_;                  // 32 KB
    unsigned char* bits = (unsigned char*)(F2 + (size_t)B_ * N_);  // 1 MB
    float* lrow  = (float*)(bits + (size_t)B_ * N_ * 128);         // 32 KB

    k_prep<<<dim3(128), 256, 0, stream>>>(W, WT);
    k_bits<<<dim3(B_ * N_ / 4), 256, 0, stream>>>(adj, bits);
    k_wh  <<<dim3(B_ * N_ / 16), 256, 0, stream>>>(h, WT, a, Bpack, F1, F2);
    k_pgen<<<dim3(B_, N_ / 16), 256, 0, stream>>>(bits, F1, F2, Apack, lrow);
    k_pv  <<<dim3(256, 2), 128, 0, stream>>>(Apack, Bpack, out);
    k_ln  <<<dim3(B_ * N_ / 8), 256, 0, stream>>>(out, lrow, gamma, beta);
}

// Round 15
// 61.462 us; speedup vs baseline: 1.1140x; 1.1140x over previous
//
#include <hip/hip_runtime.h>
#include <math.h>

#define B_    8
#define N_    1024
#define FIN   512
#define FOUT  256
#define ALPHA 0.2f
#define EPSV  1e-5f

typedef __attribute__((ext_vector_type(8))) short bf16x8;
typedef __attribute__((ext_vector_type(4))) float f32x4;

__device__ __forceinline__ short f2bf(float x) {          // RNE
    unsigned u = __builtin_bit_cast(unsigned, x);
    u = (u + 0x7FFFu + ((u >> 16) & 1u)) >> 16;
    return (short)u;
}
__device__ __forceinline__ short f2bf_fast(float x) {     // round-half-up (P path)
    unsigned u = __builtin_bit_cast(unsigned, x);
    return (short)((u + 0x8000u) >> 16);
}
__device__ __forceinline__ float bf2f(short s) {
    return __builtin_bit_cast(float, ((unsigned)(unsigned short)s) << 16);
}
__device__ __forceinline__ float gelu_exact(float x) {
    return 0.5f * x * (1.0f + erff(x * 0.70710678118654752f));
}

// Fragment-linear chunks (1 KB = 64 lanes x 16B):
//   Apack[b][m16][kt][l][u8] : lane l=(lq*16+lr) holds P[m16*16+lr][kt*32+lq*8+u]
//   Bpack[b][n16][kt][l][u8] : lane l=(lq*16+lr) holds Wh[kt*32+lq*8+u][n16*16+lr]

// ---------------------------------------------------------------------------
// k_prep: W (512x256 fp32 row-major) -> WT (256x512 bf16, [col][k]).
// ---------------------------------------------------------------------------
__global__ __launch_bounds__(256) void k_prep(const float* __restrict__ W,
                                              short* __restrict__ WT) {
    int id  = blockIdx.x * 256 + threadIdx.x;
    int col = id >> 7;
    int k4  = (id & 127) * 4;
    short4 v;
    v.x = f2bf(W[(k4 + 0) * FOUT + col]);
    v.y = f2bf(W[(k4 + 1) * FOUT + col]);
    v.z = f2bf(W[(k4 + 2) * FOUT + col]);
    v.w = f2bf(W[(k4 + 3) * FOUT + col]);
    *(short4*)(WT + (long)col * FIN + k4) = v;
}

// ---------------------------------------------------------------------------
// k_wh: Wh = h @ W via bf16 MFMA; writes Bpack (fragment-linear) + F1/F2.
// Block = 256 thr / 4 waves; 16 node-rows; grid = 512. (proven ~9 us)
// ---------------------------------------------------------------------------
__global__ __launch_bounds__(256) void k_wh(const float* __restrict__ h,
                                            const short* __restrict__ WT,
                                            const float* __restrict__ a,
                                            short* __restrict__ Bpack,
                                            float* __restrict__ F1,
                                            float* __restrict__ F2) {
    const int tid = threadIdx.x;
    const int w   = tid >> 6, l = tid & 63;
    const int lr  = l & 15, lq = l >> 4;
    const long row0 = (long)blockIdx.x * 16;
    const int colbase = w * 64;

    __shared__ float r1[4][16], r2[4][16];

    f32x4 acc[4] = {};
    const float* hrow = h + (row0 + lr) * FIN + lq * 8;

    #pragma unroll
    for (int k0 = 0; k0 < FIN; k0 += 32) {
        float4 v0 = *(const float4*)(hrow + k0);
        float4 v1 = *(const float4*)(hrow + k0 + 4);
        bf16x8 af;
        af[0] = f2bf(v0.x); af[1] = f2bf(v0.y); af[2] = f2bf(v0.z); af[3] = f2bf(v0.w);
        af[4] = f2bf(v1.x); af[5] = f2bf(v1.y); af[6] = f2bf(v1.z); af[7] = f2bf(v1.w);
        #pragma unroll
        for (int c = 0; c < 4; ++c) {
            const short* bp = WT + (long)(colbase + c * 16 + lr) * FIN + k0 + lq * 8;
            bf16x8 bf = *(const bf16x8*)bp;
            acc[c] = __builtin_amdgcn_mfma_f32_16x16x32_bf16(af, bf, acc[c], 0, 0, 0);
        }
    }

    const int b   = (int)(row0 >> 10);
    const int il0 = (int)(row0 & 1023);
    const int kt  = il0 >> 5;
    const int h16 = (il0 >> 4) & 1;
    const int lp  = (h16 * 2 + (lq >> 1)) * 16 + lr;
    const int u0  = (lq & 1) * 4;
    short* bpo = Bpack + ((long)b * 16 * 32) * 512;
    #pragma unroll
    for (int c = 0; c < 4; ++c) {
        short4 s;
        s.x = f2bf(acc[c][0]); s.y = f2bf(acc[c][1]);
        s.z = f2bf(acc[c][2]); s.w = f2bf(acc[c][3]);
        int n16 = w * 4 + c;
        *(short4*)(bpo + ((long)(n16 * 32 + kt)) * 512 + lp * 8 + u0) = s;
    }

    float p1[4] = {0.f, 0.f, 0.f, 0.f}, p2[4] = {0.f, 0.f, 0.f, 0.f};
    #pragma unroll
    for (int c = 0; c < 4; ++c) {
        int col = colbase + c * 16 + lr;
        float a1v = a[col], a2v = a[FOUT + col];
        #pragma unroll
        for (int j = 0; j < 4; ++j) { p1[j] += acc[c][j] * a1v; p2[j] += acc[c][j] * a2v; }
    }
    #pragma unroll
    for (int off = 1; off < 16; off <<= 1) {
        #pragma unroll
        for (int j = 0; j < 4; ++j) {
            p1[j] += __shfl_xor(p1[j], off, 64);
            p2[j] += __shfl_xor(p2[j], off, 64);
        }
    }
    if (lr == 0) {
        #pragma unroll
        for (int j = 0; j < 4; ++j) { r1[w][lq * 4 + j] = p1[j]; r2[w][lq * 4 + j] = p2[j]; }
    }
    __syncthreads();
    if (tid < 16) {
        F1[row0 + tid] = r1[0][tid] + r1[1][tid] + r1[2][tid] + r1[3][tid];
        F2[row0 + tid] = r2[0][tid] + r2[1][tid] + r2[2][tid] + r2[3][tid];
    }
}

// ---------------------------------------------------------------------------
// k_pgen v5 (merged bits+pgen): COALESCED adj read + direct A-frag store.
// Wave = one row; lane l reads adj[row][l*8..+7] (32B/lane, perfectly
// coalesced) for each half h: those 8 j's belong exactly to frag coords
// (kt = h*16 + (l>>2), lq = l&3). Lane computes the 8 exp values and stores
// ONE bf16x8 to Apack slot ((l&3)*16 + r)*8 in chunk kt. No ballots, no
// LDS, no barriers, no cross-lane ops. Block = 1024 thr = 16 waves = one
// m16; grid = (8, 64). f2/f1 loads are tiny + L2-hot.
//   w_ij = adj>0 ? exp(leaky(f1_i+f2_j)) : 0  (m=0 shift-invariant, <= e^27)
// ---------------------------------------------------------------------------
__global__ __launch_bounds__(1024) void k_pgen(const float* __restrict__ adj,
                                               const float* __restrict__ F1,
                                               const float* __restrict__ F2,
                                               short* __restrict__ Apack) {
    const int tid = threadIdx.x;
    const int b   = blockIdx.x;
    const int m16 = blockIdx.y;
    const int r   = tid >> 6;            // wave = row r of this m16
    const int l   = tid & 63;
    const long row = (long)b * N_ + m16 * 16 + r;

    const float f1 = F1[row];
    const float* __restrict__ arow = adj + row * N_;
    const float* __restrict__ f2b  = F2 + (long)b * N_;
    // store slot for this lane (same for both halves except kt)
    short* __restrict__ apb = Apack + (((long)b * 64 + m16) * 32) * 512
                            + ((l & 3) * 16 + r) * 8;
    const int ktlo = l >> 2;

    #pragma unroll
    for (int h = 0; h < 2; ++h) {
        const int j0 = h * 512 + l * 8;
        float4 a0  = *(const float4*)(arow + j0);
        float4 a1  = *(const float4*)(arow + j0 + 4);
        float4 f20 = *(const float4*)(f2b + j0);
        float4 f21 = *(const float4*)(f2b + j0 + 4);
        float aa[8] = {a0.x, a0.y, a0.z, a0.w, a1.x, a1.y, a1.z, a1.w};
        float ff[8] = {f20.x, f20.y, f20.z, f20.w, f21.x, f21.y, f21.z, f21.w};
        bf16x8 pv;
        #pragma unroll
        for (int u = 0; u < 8; ++u) {
            float x  = f1 + ff[u];
            float tt = fmaxf(x, ALPHA * x);
            float e  = (aa[u] > 0.f) ? __expf(tt) : 0.f;
            pv[u] = f2bf_fast(e);
        }
        *(bf16x8*)(apb + (long)(h * 16 + ktlo) * 512) = pv;
    }
}

// ---------------------------------------------------------------------------
// k_pv (R8's proven version, verbatim): pure GEMM h_prime = (Apack@Bpack)/l
// + LN + GELU. Contiguous 1KB fragment chunks, depth-1 prefetch. Block =
// 1024 thr / 16 waves = 2 rg x 4 cw x 2 kg; wave = 16 rows x 64 cols x
// K=512. Grid = (8, 32); blockIdx.x = batch pins Bpack slab to one XCD L2.
// l summed from A-frags in-loop (free VALU).
// ---------------------------------------------------------------------------
__global__ __launch_bounds__(1024, 4) void k_pv(const short* __restrict__ Apack,
                                                const short* __restrict__ Bpack,
                                                const float* __restrict__ gamma,
                                                const float* __restrict__ beta,
                                                float* __restrict__ out) {
    const int tid = threadIdx.x;
    const int b   = blockIdx.x;
    const int w   = tid >> 6, l = tid & 63;
    const int lr  = l & 15, lq = l >> 4;
    const int cw  = w & 3;          // col wave: cols cw*64..+63
    const int rg  = (w >> 2) & 1;   // row group
    const int kg  = w >> 3;         // K half
    const int m16 = blockIdx.y * 2 + rg;

    __shared__ float sc[2][4][16][68];            // cross-kg partials
    __shared__ float lnp1[2][4][16], lnp2[2][4][16];
    __shared__ float lsumS[2][2][16];             // [rg][kg][row]

    const short* ap = Apack + (((long)b * 64 + m16) * 32 + kg * 16) * 512 + l * 8;
    const short* bp = Bpack + (((long)b * 16 + cw * 4) * 32 + kg * 16) * 512 + l * 8;

    f32x4 acc[4] = {};
    float ls = 0.f;

    bf16x8 aC  = *(const bf16x8*)ap;
    bf16x8 bC0 = *(const bf16x8*)(bp);
    bf16x8 bC1 = *(const bf16x8*)(bp + 32 * 512);
    bf16x8 bC2 = *(const bf16x8*)(bp + 64 * 512);
    bf16x8 bC3 = *(const bf16x8*)(bp + 96 * 512);

    #pragma unroll
    for (int t = 0; t < 16; ++t) {
        bf16x8 aN = aC, bN0 = bC0, bN1 = bC1, bN2 = bC2, bN3 = bC3;
        if (t < 15) {
            aN  = *(const bf16x8*)(ap + (t + 1) * 512);
            bN0 = *(const bf16x8*)(bp + (t + 1) * 512);
            bN1 = *(const bf16x8*)(bp + (32 + t + 1) * 512);
            bN2 = *(const bf16x8*)(bp + (64 + t + 1) * 512);
            bN3 = *(const bf16x8*)(bp + (96 + t + 1) * 512);
        }
        #pragma unroll
        for (int u = 0; u < 8; ++u) ls += bf2f(aC[u]);   // l partial (VALU)
        acc[0] = __builtin_amdgcn_mfma_f32_16x16x32_bf16(aC, bC0, acc[0], 0, 0, 0);
        acc[1] = __builtin_amdgcn_mfma_f32_16x16x32_bf16(aC, bC1, acc[1], 0, 0, 0);
        acc[2] = __builtin_amdgcn_mfma_f32_16x16x32_bf16(aC, bC2, acc[2], 0, 0, 0);
        acc[3] = __builtin_amdgcn_mfma_f32_16x16x32_bf16(aC, bC3, acc[3], 0, 0, 0);
        aC = aN; bC0 = bN0; bC1 = bN1; bC2 = bN2; bC3 = bN3;
    }

    // row sums: reduce over lq -> every lane holds sum for row lr (this kg half)
    ls += __shfl_xor(ls, 16, 64);
    ls += __shfl_xor(ls, 32, 64);
    if (cw == 0 && lq == 0) lsumS[rg][kg][lr] = ls;

    // cross-kg reduce: kg=1 waves park partials in LDS
    if (kg == 1) {
        #pragma unroll
        for (int cf = 0; cf < 4; ++cf)
            #pragma unroll
            for (int jj = 0; jj < 4; ++jj)
                sc[rg][cw][lq * 4 + jj][cf * 16 + lr] = acc[cf][jj];
    }
    __syncthreads();

    if (kg == 0) {
        #pragma unroll
        for (int cf = 0; cf < 4; ++cf)
            #pragma unroll
            for (int jj = 0; jj < 4; ++jj)
                acc[cf][jj] += sc[rg][cw][lq * 4 + jj][cf * 16 + lr];

        // 1/l for local rows (combine kg halves)
        float il[4];
        #pragma unroll
        for (int jj = 0; jj < 4; ++jj) {
            float r = lsumS[rg][0][lq * 4 + jj] + lsumS[rg][1][lq * 4 + jj];
            il[jj] = (r > 0.f) ? 1.0f / r : 0.f;
        }
        float s1[4] = {0.f,0.f,0.f,0.f}, s2[4] = {0.f,0.f,0.f,0.f};
        #pragma unroll
        for (int cf = 0; cf < 4; ++cf)
            #pragma unroll
            for (int jj = 0; jj < 4; ++jj) {
                float v = acc[cf][jj] * il[jj];
                acc[cf][jj] = v;
                s1[jj] += v;
                s2[jj] += v * v;
            }
        #pragma unroll
        for (int off = 1; off < 16; off <<= 1)
            #pragma unroll
            for (int jj = 0; jj < 4; ++jj) {
                s1[jj] += __shfl_xor(s1[jj], off, 64);
                s2[jj] += __shfl_xor(s2[jj], off, 64);
            }
        if (lr == 0) {
            #pragma unroll
            for (int jj = 0; jj < 4; ++jj) {
                lnp1[rg][cw][lq * 4 + jj] = s1[jj];
                lnp2[rg][cw][lq * 4 + jj] = s2[jj];
            }
        }
    }
    __syncthreads();

    if (kg == 0) {
        #pragma unroll
        for (int jj = 0; jj < 4; ++jj) {
            int row = lq * 4 + jj;
            float t1 = lnp1[rg][0][row] + lnp1[rg][1][row] + lnp1[rg][2][row] + lnp1[rg][3][row];
            float t2 = lnp2[rg][0][row] + lnp2[rg][1][row] + lnp2[rg][2][row] + lnp2[rg][3][row];
            float mu   = t1 * (1.0f / FOUT);
            float rstd = rsqrtf(t2 * (1.0f / FOUT) - mu * mu + EPSV);
            #pragma unroll
            for (int cf = 0; cf < 4; ++cf) {
                int col = cw * 64 + cf * 16 + lr;
                out[((long)b * N_ + m16 * 16 + row) * FOUT + col] =
                    gelu_exact((acc[cf][jj] - mu) * rstd * gamma[col] + beta[col]);
            }
        }
    }
}

extern "C" void kernel_launch(void* const* d_in, const int* in_sizes, int n_in,
                              void* d_out, int out_size, void* d_ws, size_t ws_size,
                              hipStream_t stream) {
    const float* h     = (const float*)d_in[0];
    const float* adj   = (const float*)d_in[1];
    // d_in[2]=q_type, d_in[3]=pos : unused scalars
    const float* W     = (const float*)d_in[4];
    const float* a     = (const float*)d_in[5];
    const float* gamma = (const float*)d_in[6];
    const float* beta  = (const float*)d_in[7];
    float* out = (float*)d_out;

    // workspace layout (~20.4 MB)
    short* Apack = (short*)d_ws;                          // 8*64*32*512 = 16 MB
    short* Bpack = Apack + (size_t)B_ * 64 * 32 * 512;    // 4 MB
    short* WT    = Bpack + (size_t)B_ * 16 * 32 * 512;    // 256 KB
    float* F1    = (float*)(WT + (size_t)FOUT * FIN);     // 32 KB
    float* F2    = F1 + (size_t)B_ * N_;                  // 32 KB

    k_prep<<<dim3(128), 256, 0, stream>>>(W, WT);
    k_wh  <<<dim3(B_ * N_ / 16), 256, 0, stream>>>(h, WT, a, Bpack, F1, F2);
    k_pgen<<<dim3(B_, N_ / 16), 1024, 0, stream>>>(adj, F1, F2, Apack);
    k_pv  <<<dim3(B_, N_ / 32), 1024, 0, stream>>>(Apack, Bpack, gamma, beta, out);
}